// Round 15
// baseline (198.018 us; speedup 1.0000x reference)
//
#include <hip/hip_runtime.h>
#include <hip/hip_fp16.h>

// QuantizedLinearWhisper: E2M1 block-32 fake-quant of x and W, then x_q @ W_q^T + bias.
// M=12000 (pad 12032=47*256), K=1280, N=5120. Outputs: out[12000][5120] f32, scale_w[5120][40] f32.
//
// R15 = R11 chassis with the EXACT m201 phase rhythm: per phase, ds_reads + 1 half-tile
// stage issue BEFORE the opening barrier; then BAR; lgkmcnt(0)+sched_barrier(0); pure
// 16-MFMA cluster; BAR. Read latency drains during the barrier wait (all waves' reads
// in flight concurrently); post-barrier window is MFMA-only. vmcnt(4) publishes at
// F4/F8 ends (R11's verified ledger). 2 barriers/phase, 64-reg frag peak, XOR swizzle.

typedef _Float16 f16;
typedef _Float16 f16x8 __attribute__((ext_vector_type(8)));
typedef float f32x4 __attribute__((ext_vector_type(4)));

#define M_ROWS 12000
#define M_PAD  12032
#define N_COLS 5120
#define K_DIM  1280
#define KB     40
#define NTN    20          // N tiles of 256

#define BAR()   asm volatile("s_barrier" ::: "memory")
#define LGKM(N) asm volatile("s_waitcnt lgkmcnt(%0)" :: "i"(N) : "memory")
#define VMCNT(N) asm volatile("s_waitcnt vmcnt(%0)" :: "i"(N) : "memory")
#define SB0()   __builtin_amdgcn_sched_barrier(0)
#define GLDS(gp, lp) __builtin_amdgcn_global_load_lds( \
    (const __attribute__((address_space(1))) unsigned*)(gp), \
    (__attribute__((address_space(3))) unsigned*)(lp), 16, 0, 0)

// ---- E2M1 nearest-level (strict > boundaries, identical to reference) ----
__device__ __forceinline__ float e2m1_level(float a) {
    float lv;
    if (a > 2.5f)       lv = (a > 3.5f) ? ((a > 5.0f) ? 6.0f : 4.0f) : 3.0f;
    else if (a > 1.25f) lv = (a > 1.75f) ? 2.0f : 1.5f;
    else                lv = (a > 0.75f) ? 1.0f : ((a > 0.25f) ? 0.5f : 0.0f);
    return lv;
}

__global__ __launch_bounds__(256) void quant_x_kernel(const float* __restrict__ x,
                                                      f16* __restrict__ xq) {
    int t = blockIdx.x * blockDim.x + threadIdx.x;
    int row = t / 160;
    int c8  = t % 160;
    f16x8 o;
    if (row < M_ROWS) {
        const float* p = x + (size_t)row * K_DIM + c8 * 8;
        float v[8];
        *(float4*)&v[0] = *(const float4*)p;
        *(float4*)&v[4] = *(const float4*)(p + 4);
        float am = 0.0f;
        #pragma unroll
        for (int i = 0; i < 8; ++i) am = fmaxf(am, fabsf(v[i]));
        am = fmaxf(am, __shfl_xor(am, 1));
        am = fmaxf(am, __shfl_xor(am, 2));
        float scale = fmaxf(am / 6.0f, 1e-12f);
        #pragma unroll
        for (int i = 0; i < 8; ++i) {
            float tq = v[i] / scale;
            float q  = copysignf(e2m1_level(fabsf(tq)), tq) * scale;
            o[i] = (f16)q;
        }
    } else {
        #pragma unroll
        for (int i = 0; i < 8; ++i) o[i] = (f16)0.0f;
    }
    *(f16x8*)(xq + (size_t)row * K_DIM + c8 * 8) = o;
}

__global__ __launch_bounds__(256) void quant_w_kernel(const float* __restrict__ w,
                                                      f16* __restrict__ wq,
                                                      float* __restrict__ scale_out) {
    int t = blockIdx.x * blockDim.x + threadIdx.x;
    int row = t / 160;
    int c8  = t % 160;
    const float* p = w + (size_t)row * K_DIM + c8 * 8;
    float v[8];
    *(float4*)&v[0] = *(const float4*)p;
    *(float4*)&v[4] = *(const float4*)(p + 4);
    float am = 0.0f;
    #pragma unroll
    for (int i = 0; i < 8; ++i) am = fmaxf(am, fabsf(v[i]));
    am = fmaxf(am, __shfl_xor(am, 1));
    am = fmaxf(am, __shfl_xor(am, 2));
    float scale = fmaxf(am / 6.0f, 1e-12f);
    if ((t & 3) == 0) scale_out[row * KB + (c8 >> 2)] = scale;
    f16x8 o;
    #pragma unroll
    for (int i = 0; i < 8; ++i) {
        float tq = v[i] / scale;
        float q  = copysignf(e2m1_level(fabsf(tq)), tq) * scale;
        o[i] = (f16)q;
    }
    *(f16x8*)(wq + (size_t)row * K_DIM + c8 * 8) = o;
}

// ---- GEMM 256x256, BK=64, 8 waves 2x4, per-wave 128x64 out ----
// LDS per tile-buffer: A [256 rows][8 chunks of 16B] (32KB) + B same; chunk c of row r
// at slot (c ^ (r&7)); stage pre-swizzles the global source chunk. 128 KiB total.

__device__ __forceinline__ void stage_half(const f16* __restrict__ g, f16* l, int tid) {
    #pragma unroll
    for (int s = 0; s < 2; ++s) {
        int j = s * 512 + tid;          // chunk 0..1023 (128 rows x 8 chunks)
        int r = j >> 3;
        int c = (j & 7) ^ (r & 7);
        GLDS(g + (size_t)r * K_DIM + c * 8, l + (size_t)j * 8);
    }
}

#define READ_A(dst, buf, rbase)                                                \
    _Pragma("unroll")                                                          \
    for (int fm = 0; fm < 4; ++fm) {                                           \
        dst[fm][0] = *(const f16x8*)&(buf)[((rbase) + fm * 16) * 64 + swz[0]]; \
        dst[fm][1] = *(const f16x8*)&(buf)[((rbase) + fm * 16) * 64 + swz[1]]; \
    }
#define READ_B(dst, buf, rbase)                                                \
    _Pragma("unroll")                                                          \
    for (int fn = 0; fn < 2; ++fn) {                                           \
        dst[fn][0] = *(const f16x8*)&(buf)[((rbase) + fn * 16) * 64 + swz[0]]; \
        dst[fn][1] = *(const f16x8*)&(buf)[((rbase) + fn * 16) * 64 + swz[1]]; \
    }
#define MFMA_Q(ma, mb, mo, no)                                                 \
    __builtin_amdgcn_s_setprio(1);                                             \
    _Pragma("unroll")                                                          \
    for (int fm = 0; fm < 4; ++fm)                                             \
        _Pragma("unroll")                                                      \
        for (int fn = 0; fn < 2; ++fn) {                                       \
            acc[fm + mo][fn + no] = __builtin_amdgcn_mfma_f32_16x16x32_f16(    \
                ma[fm][0], mb[fn][0], acc[fm + mo][fn + no], 0, 0, 0);         \
            acc[fm + mo][fn + no] = __builtin_amdgcn_mfma_f32_16x16x32_f16(    \
                ma[fm][1], mb[fn][1], acc[fm + mo][fn + no], 0, 0, 0);         \
        }                                                                      \
    __builtin_amdgcn_s_setprio(0);

// One iteration = tiles 2i (buf0) and 2i+1 (buf1).
// Phase rhythm (m201): {reads; stage; [lgkm(8) on 12-read phases]; BAR; lgkm0+SB0;
// MFMA x16; BAR}. Stage slots (WAR-verified, R11): F1:A(2i+1).lo F2:A(2i+1).hi
// F3:B(2i+2).lo F4:A(2i+2).lo F5:A(2i+2).hi F6:B(2i+2).hi F7:B(2i+3).lo F8:B(2i+3).hi.
// vmcnt(V4) end-F4 publishes tile 2i+1; vmcnt(4) end-F8 publishes tile 2i+2.
template<bool SREST, int V4>
__device__ __forceinline__ void iter8(f16* A0, f16* B0, f16* A1, f16* B1,
                                      const f16* gA1, const f16* gA2,
                                      const f16* gB2, const f16* gB3,
                                      f32x4 (&acc)[8][4],
                                      int tid, int arow0, int brow0, const int (&swz)[2]) {
    f16x8 aLO[4][2], aHI[4][2], bLO[2][2], bHI[2][2];

    // ---- F1: reads aLO+bLO (12); stage A(2i+1).lo -> buf1
    READ_A(aLO, A0, arow0);
    READ_B(bLO, B0, brow0);
    stage_half(gA1, A1, tid);
    LGKM(8);
    BAR();
    LGKM(0); SB0();
    MFMA_Q(aLO, bLO, 0, 0);
    BAR();
    // ---- F2: reads bHI (4); stage A(2i+1).hi
    READ_B(bHI, B0, brow0 + 32);
    stage_half(gA1 + 128 * K_DIM, A1 + 8192, tid);
    BAR();
    LGKM(0); SB0();
    MFMA_Q(aLO, bHI, 0, 2);
    BAR();
    // ---- F3: reads aHI (8); stage B(2i+2).lo -> buf0 (B0 reads complete by F2 lgkm0+BAR)
    READ_A(aHI, A0, arow0 + 64);
    if (SREST) stage_half(gB2, B0, tid);
    BAR();
    LGKM(0); SB0();
    MFMA_Q(aHI, bHI, 4, 2);
    BAR();
    // ---- F4: stage A(2i+2).lo -> buf0 (A0 reads complete by F3 lgkm0+BAR); Q4;
    //          publish tile 2i+1
    if (SREST) stage_half(gA2, A0, tid);
    BAR();
    MFMA_Q(aHI, bLO, 4, 0);
    VMCNT(V4);
    BAR();
    // ---- F5: reads aLO+bLO of tile 2i+1 (12); stage A(2i+2).hi
    READ_A(aLO, A1, arow0);
    READ_B(bLO, B1, brow0);
    if (SREST) stage_half(gA2 + 128 * K_DIM, A0 + 8192, tid);
    LGKM(8);
    BAR();
    LGKM(0); SB0();
    MFMA_Q(aLO, bLO, 0, 0);
    BAR();
    // ---- F6: reads bHI (4); stage B(2i+2).hi
    READ_B(bHI, B1, brow0 + 32);
    if (SREST) stage_half(gB2 + 128 * K_DIM, B0 + 8192, tid);
    BAR();
    LGKM(0); SB0();
    MFMA_Q(aLO, bHI, 0, 2);
    BAR();
    // ---- F7: reads aHI (8); stage B(2i+3).lo -> buf1 (B1 reads complete by F6)
    READ_A(aHI, A1, arow0 + 64);
    if (SREST) stage_half(gB3, B1, tid);
    BAR();
    LGKM(0); SB0();
    MFMA_Q(aHI, bHI, 4, 2);
    BAR();
    // ---- F8: stage B(2i+3).hi; Q4; publish tile 2i+2
    if (SREST) stage_half(gB3 + 128 * K_DIM, B1 + 8192, tid);
    BAR();
    MFMA_Q(aHI, bLO, 4, 0);
    if (SREST) VMCNT(4);
    BAR();
}

__global__ __launch_bounds__(512, 2) void gemm_kernel(const f16* __restrict__ A,
                                                      const f16* __restrict__ B,
                                                      const float* __restrict__ bias,
                                                      float* __restrict__ C) {
    extern __shared__ f16 sm[];            // 2 tile-bufs x (A 16384 + B 16384 f16) = 128 KiB
    int mt = blockIdx.x / NTN;
    int nt = blockIdx.x % NTN;

    int tid  = threadIdx.x;
    int lane = tid & 63;
    int wid  = tid >> 6;
    int wr   = wid >> 2;                   // 0..1
    int wc   = wid & 3;                    // 0..3
    int l15  = lane & 15;

    int swz[2] = { (((lane >> 4)    ) ^ (lane & 7)) * 8,
                   (((lane >> 4) + 4) ^ (lane & 7)) * 8 };
    int arow0 = wr * 128 + l15;
    int brow0 = wc * 64 + l15;

    const f16* gAb = A + (size_t)(mt * 256) * K_DIM;
    const f16* gBb = B + (size_t)(nt * 256) * K_DIM;

    f16* A0 = sm;
    f16* B0 = sm + 16384;
    f16* A1 = sm + 32768;
    f16* B1 = sm + 49152;

    f32x4 acc[8][4] = {};

    // prologue: stage tile0 fully + tile1's B (slot order B0lo,A0lo,A0hi,B0hi,B1lo,B1hi);
    // vmcnt(4) publishes tile0; B1 stays in flight (drained at F4(0)'s vmcnt(4)).
    stage_half(gBb,               B0,        tid);
    stage_half(gAb,               A0,        tid);
    stage_half(gAb + 128 * K_DIM, A0 + 8192, tid);
    stage_half(gBb + 128 * K_DIM, B0 + 8192, tid);
    stage_half(gBb + 64,               B1,        tid);
    stage_half(gBb + 64 + 128 * K_DIM, B1 + 8192, tid);
    VMCNT(4);
    BAR();

    for (int i = 0; i < 9; ++i) {
        const f16* gA1 = gAb + (2 * i + 1) * 64;
        const f16* gA2 = gAb + (2 * i + 2) * 64;
        const f16* gB2 = gBb + (2 * i + 2) * 64;
        const f16* gB3 = gBb + (2 * i + 3) * 64;
        iter8<true, 4>(A0, B0, A1, B1, gA1, gA2, gB2, gB3,
                       acc, tid, arow0, brow0, swz);
    }
    // last iteration (tiles 18,19): stage only A19 (F1/F2); publish with vmcnt(0)
    iter8<false, 0>(A0, B0, A1, B1, gAb + 19 * 64, gAb, gBb, gBb,
                    acc, tid, arow0, brow0, swz);

    // ---- epilogue: C = acc + bias.  C/D layout: col=lane&15, row=(lane>>4)*4+j
    int crow0 = mt * 256 + wr * 128;
    int ccol  = nt * 256 + wc * 64 + l15;
    float bz[4];
    #pragma unroll
    for (int fn = 0; fn < 4; ++fn) bz[fn] = bias[ccol + fn * 16];

    #pragma unroll
    for (int fm = 0; fm < 8; ++fm) {
        #pragma unroll
        for (int j = 0; j < 4; ++j) {
            int row = crow0 + fm * 16 + (lane >> 4) * 4 + j;
            if (row < M_ROWS) {
                float* cp = C + (size_t)row * N_COLS + ccol;
                #pragma unroll
                for (int fn = 0; fn < 4; ++fn)
                    cp[fn * 16] = acc[fm][fn][j] + bz[fn];
            }
        }
    }
}

extern "C" void kernel_launch(void* const* d_in, const int* in_sizes, int n_in,
                              void* d_out, int out_size, void* d_ws, size_t ws_size,
                              hipStream_t stream) {
    const float* x      = (const float*)d_in[0];
    const float* weight = (const float*)d_in[1];
    const float* bias   = (const float*)d_in[2];
    float* out     = (float*)d_out;
    float* scale_w = (float*)d_out + (size_t)M_ROWS * N_COLS;

    f16* xq = (f16*)d_ws;
    f16* wq = (f16*)((char*)d_ws + (size_t)M_PAD * K_DIM * sizeof(f16));

    (void)hipFuncSetAttribute((const void*)gemm_kernel,
                              hipFuncAttributeMaxDynamicSharedMemorySize, 131072);

    {
        int threads = M_PAD * (K_DIM / 8);
        quant_x_kernel<<<threads / 256, 256, 0, stream>>>(x, xq);
    }
    {
        int threads = N_COLS * (K_DIM / 8);
        quant_w_kernel<<<threads / 256, 256, 0, stream>>>(weight, wq, scale_w);
    }
    {
        int grid = (M_PAD / 256) * (N_COLS / 256);   // 47 * 20 = 940
        gemm_kernel<<<grid, 512, 131072, stream>>>(xq, wq, bias, out);
    }
}

// Round 16
// 193.885 us; speedup vs baseline: 1.0213x; 1.0213x over previous
//
#include <hip/hip_runtime.h>
#include <hip/hip_fp16.h>

// QuantizedLinearWhisper: E2M1 block-32 fake-quant of x and W, then x_q @ W_q^T + bias.
// M=12000 (pad 12032=47*256), K=1280, N=5120. Outputs: out[12000][5120] f32, scale_w[5120][40] f32.
//
// R16 = R11 (best measured: GEMM 167us, 944 TF, MfmaUtil 42.5%, zero spill)
//  + bijective XCD-aware block swizzle (m204 variant; 940 = 8*117+4 not divisible by 8)
//  + fused quant kernel (single launch for x and w quantization).
// R11 core: 256x256, BK=64, 8 waves (2x4), 1 block/CU, 8-phase schedule
// {stage 1 half-tile; ds-read this phase's operands; MFMA 16; BAR}, vmcnt(4) publishes
// only at phases 4/8, raw s_barrier, setprio on MFMA, XOR chunk swizzle (0 conflicts).

typedef _Float16 f16;
typedef _Float16 f16x8 __attribute__((ext_vector_type(8)));
typedef float f32x4 __attribute__((ext_vector_type(4)));

#define M_ROWS 12000
#define M_PAD  12032
#define N_COLS 5120
#define K_DIM  1280
#define KB     40
#define NTN    20          // N tiles of 256
#define XBLK   7520        // quant_x blocks: 12032*160/256

#define BAR()   asm volatile("s_barrier" ::: "memory")
#define VMCNT(N) asm volatile("s_waitcnt vmcnt(%0)" :: "i"(N) : "memory")
#define GLDS(gp, lp) __builtin_amdgcn_global_load_lds( \
    (const __attribute__((address_space(1))) unsigned*)(gp), \
    (__attribute__((address_space(3))) unsigned*)(lp), 16, 0, 0)

// ---- E2M1 nearest-level (strict > boundaries, identical to reference) ----
__device__ __forceinline__ float e2m1_level(float a) {
    float lv;
    if (a > 2.5f)       lv = (a > 3.5f) ? ((a > 5.0f) ? 6.0f : 4.0f) : 3.0f;
    else if (a > 1.25f) lv = (a > 1.75f) ? 2.0f : 1.5f;
    else                lv = (a > 0.75f) ? 1.0f : ((a > 0.25f) ? 0.5f : 0.0f);
    return lv;
}

// Fused quantization: blocks [0,XBLK) quantize x -> xq (padded); rest quantize w -> wq + scales.
__global__ __launch_bounds__(256) void quant_fused(const float* __restrict__ x,
                                                   f16* __restrict__ xq,
                                                   const float* __restrict__ w,
                                                   f16* __restrict__ wq,
                                                   float* __restrict__ scale_out) {
    int b = blockIdx.x;
    if (b < XBLK) {
        int t = b * 256 + threadIdx.x;
        int row = t / 160;
        int c8  = t % 160;
        f16x8 o;
        if (row < M_ROWS) {
            const float* p = x + (size_t)row * K_DIM + c8 * 8;
            float v[8];
            *(float4*)&v[0] = *(const float4*)p;
            *(float4*)&v[4] = *(const float4*)(p + 4);
            float am = 0.0f;
            #pragma unroll
            for (int i = 0; i < 8; ++i) am = fmaxf(am, fabsf(v[i]));
            am = fmaxf(am, __shfl_xor(am, 1));
            am = fmaxf(am, __shfl_xor(am, 2));
            float scale = fmaxf(am / 6.0f, 1e-12f);
            #pragma unroll
            for (int i = 0; i < 8; ++i) {
                float tq = v[i] / scale;
                float q  = copysignf(e2m1_level(fabsf(tq)), tq) * scale;
                o[i] = (f16)q;
            }
        } else {
            #pragma unroll
            for (int i = 0; i < 8; ++i) o[i] = (f16)0.0f;
        }
        *(f16x8*)(xq + (size_t)row * K_DIM + c8 * 8) = o;
    } else {
        int t = (b - XBLK) * 256 + threadIdx.x;
        int row = t / 160;
        int c8  = t % 160;
        const float* p = w + (size_t)row * K_DIM + c8 * 8;
        float v[8];
        *(float4*)&v[0] = *(const float4*)p;
        *(float4*)&v[4] = *(const float4*)(p + 4);
        float am = 0.0f;
        #pragma unroll
        for (int i = 0; i < 8; ++i) am = fmaxf(am, fabsf(v[i]));
        am = fmaxf(am, __shfl_xor(am, 1));
        am = fmaxf(am, __shfl_xor(am, 2));
        float scale = fmaxf(am / 6.0f, 1e-12f);
        if ((t & 3) == 0) scale_out[row * KB + (c8 >> 2)] = scale;
        f16x8 o;
        #pragma unroll
        for (int i = 0; i < 8; ++i) {
            float tq = v[i] / scale;
            float q  = copysignf(e2m1_level(fabsf(tq)), tq) * scale;
            o[i] = (f16)q;
        }
        *(f16x8*)(wq + (size_t)row * K_DIM + c8 * 8) = o;
    }
}

// ---- GEMM 256x256, BK=64, 8 waves 2x4, per-wave 128x64 out ----
// LDS per tile-buffer: A [256 rows][8 chunks of 16B] (32KB) + B same; chunk c of row r
// at slot (c ^ (r&7)); stage pre-swizzles the global source chunk. 128 KiB total.

__device__ __forceinline__ void stage_half(const f16* __restrict__ g, f16* l, int tid) {
    #pragma unroll
    for (int s = 0; s < 2; ++s) {
        int j = s * 512 + tid;          // chunk 0..1023 (128 rows x 8 chunks)
        int r = j >> 3;
        int c = (j & 7) ^ (r & 7);
        GLDS(g + (size_t)r * K_DIM + c * 8, l + (size_t)j * 8);
    }
}

#define READ_A(dst, buf, rbase)                                                \
    _Pragma("unroll")                                                          \
    for (int fm = 0; fm < 4; ++fm) {                                           \
        dst[fm][0] = *(const f16x8*)&(buf)[((rbase) + fm * 16) * 64 + swz[0]]; \
        dst[fm][1] = *(const f16x8*)&(buf)[((rbase) + fm * 16) * 64 + swz[1]]; \
    }
#define READ_B(dst, buf, rbase)                                                \
    _Pragma("unroll")                                                          \
    for (int fn = 0; fn < 2; ++fn) {                                           \
        dst[fn][0] = *(const f16x8*)&(buf)[((rbase) + fn * 16) * 64 + swz[0]]; \
        dst[fn][1] = *(const f16x8*)&(buf)[((rbase) + fn * 16) * 64 + swz[1]]; \
    }
#define MFMA_Q(ma, mb, mo, no)                                                 \
    __builtin_amdgcn_s_setprio(1);                                             \
    _Pragma("unroll")                                                          \
    for (int fm = 0; fm < 4; ++fm)                                             \
        _Pragma("unroll")                                                      \
        for (int fn = 0; fn < 2; ++fn) {                                       \
            acc[fm + mo][fn + no] = __builtin_amdgcn_mfma_f32_16x16x32_f16(    \
                ma[fm][0], mb[fn][0], acc[fm + mo][fn + no], 0, 0, 0);         \
            acc[fm + mo][fn + no] = __builtin_amdgcn_mfma_f32_16x16x32_f16(    \
                ma[fm][1], mb[fn][1], acc[fm + mo][fn + no], 0, 0, 0);         \
        }                                                                      \
    __builtin_amdgcn_s_setprio(0);

// One iteration = tiles 2i (buf0) and 2i+1 (buf1), stages per slot table.
// SREST gates slots F3..F8 (tiles 2i+2, 2i+3); V4 = vmcnt at end of F4.
template<bool SREST, int V4>
__device__ __forceinline__ void iter8(f16* A0, f16* B0, f16* A1, f16* B1,
                                      const f16* gA1, const f16* gA2,
                                      const f16* gB2, const f16* gB3,
                                      f32x4 (&acc)[8][4],
                                      int tid, int arow0, int brow0, const int (&swz)[2]) {
    f16x8 aLO[4][2], aHI[4][2], bLO[2][2], bHI[2][2];

    // ---- F1: stage A(2i+1).lo -> buf1; read aLO+bLO (tile 2i); Q1
    stage_half(gA1, A1, tid);
    READ_A(aLO, A0, arow0);
    READ_B(bLO, B0, brow0);
    MFMA_Q(aLO, bLO, 0, 0);
    BAR();
    // ---- F2: stage A(2i+1).hi; read bHI; Q2
    stage_half(gA1 + 128 * K_DIM, A1 + 8192, tid);
    READ_B(bHI, B0, brow0 + 32);
    MFMA_Q(aLO, bHI, 0, 2);
    BAR();
    // ---- F3: stage B(2i+2).lo -> buf0 (B0 reads done F2); read aHI; Q3
    if (SREST) stage_half(gB2, B0, tid);
    READ_A(aHI, A0, arow0 + 64);
    MFMA_Q(aHI, bHI, 4, 2);
    BAR();
    // ---- F4: stage A(2i+2).lo -> buf0 (A0 reads done F3); Q4; publish tile 2i+1
    if (SREST) stage_half(gA2, A0, tid);
    MFMA_Q(aHI, bLO, 4, 0);
    VMCNT(V4);
    BAR();
    // ---- F5: stage A(2i+2).hi; read aLO+bLO (tile 2i+1); Q1
    if (SREST) stage_half(gA2 + 128 * K_DIM, A0 + 8192, tid);
    READ_A(aLO, A1, arow0);
    READ_B(bLO, B1, brow0);
    MFMA_Q(aLO, bLO, 0, 0);
    BAR();
    // ---- F6: stage B(2i+2).hi; read bHI; Q2
    if (SREST) stage_half(gB2 + 128 * K_DIM, B0 + 8192, tid);
    READ_B(bHI, B1, brow0 + 32);
    MFMA_Q(aLO, bHI, 0, 2);
    BAR();
    // ---- F7: stage B(2i+3).lo -> buf1 (B1 reads done F6); read aHI; Q3
    if (SREST) stage_half(gB3, B1, tid);
    READ_A(aHI, A1, arow0 + 64);
    MFMA_Q(aHI, bHI, 4, 2);
    BAR();
    // ---- F8: stage B(2i+3).hi; Q4; publish tile 2i+2
    if (SREST) stage_half(gB3 + 128 * K_DIM, B1 + 8192, tid);
    MFMA_Q(aHI, bLO, 4, 0);
    if (SREST) VMCNT(4);
    BAR();
}

__global__ __launch_bounds__(512, 2) void gemm_kernel(const f16* __restrict__ A,
                                                      const f16* __restrict__ B,
                                                      const float* __restrict__ bias,
                                                      float* __restrict__ C) {
    extern __shared__ f16 sm[];            // 2 tile-bufs x (A 16384 + B 16384 f16) = 128 KiB

    // Bijective XCD swizzle (m204): 940 = 8*117 + 4; xcd<4 get 118 blocks, else 117.
    // Each XCD owns a contiguous wgid chunk (~6 mt-rows) -> A-panels L2-resident.
    int orig = blockIdx.x;
    int xcd  = orig & 7;
    int loc  = orig >> 3;
    int wgid = (xcd < 4 ? xcd * 118 : 472 + (xcd - 4) * 117) + loc;
    int mt = wgid / NTN;
    int nt = wgid % NTN;

    int tid  = threadIdx.x;
    int lane = tid & 63;
    int wid  = tid >> 6;
    int wr   = wid >> 2;                   // 0..1
    int wc   = wid & 3;                    // 0..3
    int l15  = lane & 15;

    int swz[2] = { (((lane >> 4)    ) ^ (lane & 7)) * 8,
                   (((lane >> 4) + 4) ^ (lane & 7)) * 8 };
    int arow0 = wr * 128 + l15;
    int brow0 = wc * 64 + l15;

    const f16* gAb = A + (size_t)(mt * 256) * K_DIM;
    const f16* gBb = B + (size_t)(nt * 256) * K_DIM;

    f16* A0 = sm;
    f16* B0 = sm + 16384;
    f16* A1 = sm + 32768;
    f16* B1 = sm + 49152;

    f32x4 acc[8][4] = {};

    // prologue: stage tile0 fully + tile1's B (slot order B0lo,A0lo,A0hi,B0hi,B1lo,B1hi);
    // vmcnt(4) publishes tile0; B1 stays in flight (drained at F4(0)'s vmcnt(4)).
    stage_half(gBb,               B0,        tid);
    stage_half(gAb,               A0,        tid);
    stage_half(gAb + 128 * K_DIM, A0 + 8192, tid);
    stage_half(gBb + 128 * K_DIM, B0 + 8192, tid);
    stage_half(gBb + 64,               B1,        tid);
    stage_half(gBb + 64 + 128 * K_DIM, B1 + 8192, tid);
    VMCNT(4);
    BAR();

    for (int i = 0; i < 9; ++i) {
        const f16* gA1 = gAb + (2 * i + 1) * 64;
        const f16* gA2 = gAb + (2 * i + 2) * 64;
        const f16* gB2 = gBb + (2 * i + 2) * 64;
        const f16* gB3 = gBb + (2 * i + 3) * 64;
        iter8<true, 4>(A0, B0, A1, B1, gA1, gA2, gB2, gB3,
                       acc, tid, arow0, brow0, swz);
    }
    // last iteration (tiles 18,19): stage only A19 (F1/F2); publish with vmcnt(0)
    iter8<false, 0>(A0, B0, A1, B1, gAb + 19 * 64, gAb, gBb, gBb,
                    acc, tid, arow0, brow0, swz);

    // ---- epilogue: C = acc + bias.  C/D layout: col=lane&15, row=(lane>>4)*4+j
    int crow0 = mt * 256 + wr * 128;
    int ccol  = nt * 256 + wc * 64 + l15;
    float bz[4];
    #pragma unroll
    for (int fn = 0; fn < 4; ++fn) bz[fn] = bias[ccol + fn * 16];

    #pragma unroll
    for (int fm = 0; fm < 8; ++fm) {
        #pragma unroll
        for (int j = 0; j < 4; ++j) {
            int row = crow0 + fm * 16 + (lane >> 4) * 4 + j;
            if (row < M_ROWS) {
                float* cp = C + (size_t)row * N_COLS + ccol;
                #pragma unroll
                for (int fn = 0; fn < 4; ++fn)
                    cp[fn * 16] = acc[fm][fn][j] + bz[fn];
            }
        }
    }
}

extern "C" void kernel_launch(void* const* d_in, const int* in_sizes, int n_in,
                              void* d_out, int out_size, void* d_ws, size_t ws_size,
                              hipStream_t stream) {
    const float* x      = (const float*)d_in[0];
    const float* weight = (const float*)d_in[1];
    const float* bias   = (const float*)d_in[2];
    float* out     = (float*)d_out;
    float* scale_w = (float*)d_out + (size_t)M_ROWS * N_COLS;

    f16* xq = (f16*)d_ws;
    f16* wq = (f16*)((char*)d_ws + (size_t)M_PAD * K_DIM * sizeof(f16));

    (void)hipFuncSetAttribute((const void*)gemm_kernel,
                              hipFuncAttributeMaxDynamicSharedMemorySize, 131072);

    {
        int wblocks = N_COLS * (K_DIM / 8) / 256;    // 3200
        quant_fused<<<XBLK + wblocks, 256, 0, stream>>>(x, xq, weight, wq, scale_w);
    }
    {
        int grid = (M_PAD / 256) * (N_COLS / 256);   // 47 * 20 = 940
        gemm_kernel<<<grid, 512, 131072, stream>>>(xq, wq, bias, out);
    }
}

// Round 17
// 189.765 us; speedup vs baseline: 1.0435x; 1.0217x over previous
//
#include <hip/hip_runtime.h>
#include <hip/hip_fp16.h>

// QuantizedLinearWhisper: E2M1 block-32 fake-quant of x and W, then x_q @ W_q^T + bias.
// M=12000 (pad 12032=47*256), K=1280, N=5120. Outputs: out[12000][5120] f32, scale_w[5120][40] f32.
//
// R17 = R11 GEMM core (best measured: 167us, 944 TF, MfmaUtil 42.5%, zero spill,
// identity block mapping — R16 showed XCD-chunk swizzle inflates FETCH +29% on this
// L3-fit workload) + fused single-launch quantization (R16's win, ~5us).
// GEMM: 256x256, BK=64, 8 waves (2x4), 1 block/CU, 8-phase schedule
// {stage 1 half-tile; ds-read this phase's operands; MFMA 16; BAR}, vmcnt(4) publishes
// only at phases 4/8, raw s_barrier, setprio on MFMA, XOR chunk swizzle (0 conflicts).

typedef _Float16 f16;
typedef _Float16 f16x8 __attribute__((ext_vector_type(8)));
typedef float f32x4 __attribute__((ext_vector_type(4)));

#define M_ROWS 12000
#define M_PAD  12032
#define N_COLS 5120
#define K_DIM  1280
#define KB     40
#define NTN    20          // N tiles of 256
#define XBLK   7520        // quant_x blocks: 12032*160/256

#define BAR()   asm volatile("s_barrier" ::: "memory")
#define VMCNT(N) asm volatile("s_waitcnt vmcnt(%0)" :: "i"(N) : "memory")
#define GLDS(gp, lp) __builtin_amdgcn_global_load_lds( \
    (const __attribute__((address_space(1))) unsigned*)(gp), \
    (__attribute__((address_space(3))) unsigned*)(lp), 16, 0, 0)

// ---- E2M1 nearest-level (strict > boundaries, identical to reference) ----
__device__ __forceinline__ float e2m1_level(float a) {
    float lv;
    if (a > 2.5f)       lv = (a > 3.5f) ? ((a > 5.0f) ? 6.0f : 4.0f) : 3.0f;
    else if (a > 1.25f) lv = (a > 1.75f) ? 2.0f : 1.5f;
    else                lv = (a > 0.75f) ? 1.0f : ((a > 0.25f) ? 0.5f : 0.0f);
    return lv;
}

// Fused quantization: blocks [0,XBLK) quantize x -> xq (padded); rest quantize w -> wq + scales.
__global__ __launch_bounds__(256) void quant_fused(const float* __restrict__ x,
                                                   f16* __restrict__ xq,
                                                   const float* __restrict__ w,
                                                   f16* __restrict__ wq,
                                                   float* __restrict__ scale_out) {
    int b = blockIdx.x;
    if (b < XBLK) {
        int t = b * 256 + threadIdx.x;
        int row = t / 160;
        int c8  = t % 160;
        f16x8 o;
        if (row < M_ROWS) {
            const float* p = x + (size_t)row * K_DIM + c8 * 8;
            float v[8];
            *(float4*)&v[0] = *(const float4*)p;
            *(float4*)&v[4] = *(const float4*)(p + 4);
            float am = 0.0f;
            #pragma unroll
            for (int i = 0; i < 8; ++i) am = fmaxf(am, fabsf(v[i]));
            am = fmaxf(am, __shfl_xor(am, 1));
            am = fmaxf(am, __shfl_xor(am, 2));
            float scale = fmaxf(am / 6.0f, 1e-12f);
            #pragma unroll
            for (int i = 0; i < 8; ++i) {
                float tq = v[i] / scale;
                float q  = copysignf(e2m1_level(fabsf(tq)), tq) * scale;
                o[i] = (f16)q;
            }
        } else {
            #pragma unroll
            for (int i = 0; i < 8; ++i) o[i] = (f16)0.0f;
        }
        *(f16x8*)(xq + (size_t)row * K_DIM + c8 * 8) = o;
    } else {
        int t = (b - XBLK) * 256 + threadIdx.x;
        int row = t / 160;
        int c8  = t % 160;
        const float* p = w + (size_t)row * K_DIM + c8 * 8;
        float v[8];
        *(float4*)&v[0] = *(const float4*)p;
        *(float4*)&v[4] = *(const float4*)(p + 4);
        float am = 0.0f;
        #pragma unroll
        for (int i = 0; i < 8; ++i) am = fmaxf(am, fabsf(v[i]));
        am = fmaxf(am, __shfl_xor(am, 1));
        am = fmaxf(am, __shfl_xor(am, 2));
        float scale = fmaxf(am / 6.0f, 1e-12f);
        if ((t & 3) == 0) scale_out[row * KB + (c8 >> 2)] = scale;
        f16x8 o;
        #pragma unroll
        for (int i = 0; i < 8; ++i) {
            float tq = v[i] / scale;
            float q  = copysignf(e2m1_level(fabsf(tq)), tq) * scale;
            o[i] = (f16)q;
        }
        *(f16x8*)(wq + (size_t)row * K_DIM + c8 * 8) = o;
    }
}

// ---- GEMM 256x256, BK=64, 8 waves 2x4, per-wave 128x64 out ----
// LDS per tile-buffer: A [256 rows][8 chunks of 16B] (32KB) + B same; chunk c of row r
// at slot (c ^ (r&7)); stage pre-swizzles the global source chunk. 128 KiB total.

__device__ __forceinline__ void stage_half(const f16* __restrict__ g, f16* l, int tid) {
    #pragma unroll
    for (int s = 0; s < 2; ++s) {
        int j = s * 512 + tid;          // chunk 0..1023 (128 rows x 8 chunks)
        int r = j >> 3;
        int c = (j & 7) ^ (r & 7);
        GLDS(g + (size_t)r * K_DIM + c * 8, l + (size_t)j * 8);
    }
}

#define READ_A(dst, buf, rbase)                                                \
    _Pragma("unroll")                                                          \
    for (int fm = 0; fm < 4; ++fm) {                                           \
        dst[fm][0] = *(const f16x8*)&(buf)[((rbase) + fm * 16) * 64 + swz[0]]; \
        dst[fm][1] = *(const f16x8*)&(buf)[((rbase) + fm * 16) * 64 + swz[1]]; \
    }
#define READ_B(dst, buf, rbase)                                                \
    _Pragma("unroll")                                                          \
    for (int fn = 0; fn < 2; ++fn) {                                           \
        dst[fn][0] = *(const f16x8*)&(buf)[((rbase) + fn * 16) * 64 + swz[0]]; \
        dst[fn][1] = *(const f16x8*)&(buf)[((rbase) + fn * 16) * 64 + swz[1]]; \
    }
#define MFMA_Q(ma, mb, mo, no)                                                 \
    __builtin_amdgcn_s_setprio(1);                                             \
    _Pragma("unroll")                                                          \
    for (int fm = 0; fm < 4; ++fm)                                             \
        _Pragma("unroll")                                                      \
        for (int fn = 0; fn < 2; ++fn) {                                       \
            acc[fm + mo][fn + no] = __builtin_amdgcn_mfma_f32_16x16x32_f16(    \
                ma[fm][0], mb[fn][0], acc[fm + mo][fn + no], 0, 0, 0);         \
            acc[fm + mo][fn + no] = __builtin_amdgcn_mfma_f32_16x16x32_f16(    \
                ma[fm][1], mb[fn][1], acc[fm + mo][fn + no], 0, 0, 0);         \
        }                                                                      \
    __builtin_amdgcn_s_setprio(0);

// One iteration = tiles 2i (buf0) and 2i+1 (buf1), stages per slot table.
// SREST gates slots F3..F8 (tiles 2i+2, 2i+3); V4 = vmcnt at end of F4.
template<bool SREST, int V4>
__device__ __forceinline__ void iter8(f16* A0, f16* B0, f16* A1, f16* B1,
                                      const f16* gA1, const f16* gA2,
                                      const f16* gB2, const f16* gB3,
                                      f32x4 (&acc)[8][4],
                                      int tid, int arow0, int brow0, const int (&swz)[2]) {
    f16x8 aLO[4][2], aHI[4][2], bLO[2][2], bHI[2][2];

    // ---- F1: stage A(2i+1).lo -> buf1; read aLO+bLO (tile 2i); Q1
    stage_half(gA1, A1, tid);
    READ_A(aLO, A0, arow0);
    READ_B(bLO, B0, brow0);
    MFMA_Q(aLO, bLO, 0, 0);
    BAR();
    // ---- F2: stage A(2i+1).hi; read bHI; Q2
    stage_half(gA1 + 128 * K_DIM, A1 + 8192, tid);
    READ_B(bHI, B0, brow0 + 32);
    MFMA_Q(aLO, bHI, 0, 2);
    BAR();
    // ---- F3: stage B(2i+2).lo -> buf0 (B0 reads done F2); read aHI; Q3
    if (SREST) stage_half(gB2, B0, tid);
    READ_A(aHI, A0, arow0 + 64);
    MFMA_Q(aHI, bHI, 4, 2);
    BAR();
    // ---- F4: stage A(2i+2).lo -> buf0 (A0 reads done F3); Q4; publish tile 2i+1
    if (SREST) stage_half(gA2, A0, tid);
    MFMA_Q(aHI, bLO, 4, 0);
    VMCNT(V4);
    BAR();
    // ---- F5: stage A(2i+2).hi; read aLO+bLO (tile 2i+1); Q1
    if (SREST) stage_half(gA2 + 128 * K_DIM, A0 + 8192, tid);
    READ_A(aLO, A1, arow0);
    READ_B(bLO, B1, brow0);
    MFMA_Q(aLO, bLO, 0, 0);
    BAR();
    // ---- F6: stage B(2i+2).hi; read bHI; Q2
    if (SREST) stage_half(gB2 + 128 * K_DIM, B0 + 8192, tid);
    READ_B(bHI, B1, brow0 + 32);
    MFMA_Q(aLO, bHI, 0, 2);
    BAR();
    // ---- F7: stage B(2i+3).lo -> buf1 (B1 reads done F6); read aHI; Q3
    if (SREST) stage_half(gB3, B1, tid);
    READ_A(aHI, A1, arow0 + 64);
    MFMA_Q(aHI, bHI, 4, 2);
    BAR();
    // ---- F8: stage B(2i+3).hi; Q4; publish tile 2i+2
    if (SREST) stage_half(gB3 + 128 * K_DIM, B1 + 8192, tid);
    MFMA_Q(aHI, bLO, 4, 0);
    if (SREST) VMCNT(4);
    BAR();
}

__global__ __launch_bounds__(512, 2) void gemm_kernel(const f16* __restrict__ A,
                                                      const f16* __restrict__ B,
                                                      const float* __restrict__ bias,
                                                      float* __restrict__ C) {
    extern __shared__ f16 sm[];            // 2 tile-bufs x (A 16384 + B 16384 f16) = 128 KiB
    int mt = blockIdx.x / NTN;             // identity mapping (R16's XCD swizzle hurt: +29% FETCH)
    int nt = blockIdx.x % NTN;

    int tid  = threadIdx.x;
    int lane = tid & 63;
    int wid  = tid >> 6;
    int wr   = wid >> 2;                   // 0..1
    int wc   = wid & 3;                    // 0..3
    int l15  = lane & 15;

    int swz[2] = { (((lane >> 4)    ) ^ (lane & 7)) * 8,
                   (((lane >> 4) + 4) ^ (lane & 7)) * 8 };
    int arow0 = wr * 128 + l15;
    int brow0 = wc * 64 + l15;

    const f16* gAb = A + (size_t)(mt * 256) * K_DIM;
    const f16* gBb = B + (size_t)(nt * 256) * K_DIM;

    f16* A0 = sm;
    f16* B0 = sm + 16384;
    f16* A1 = sm + 32768;
    f16* B1 = sm + 49152;

    f32x4 acc[8][4] = {};

    // prologue: stage tile0 fully + tile1's B (slot order B0lo,A0lo,A0hi,B0hi,B1lo,B1hi);
    // vmcnt(4) publishes tile0; B1 stays in flight (drained at F4(0)'s vmcnt(4)).
    stage_half(gBb,               B0,        tid);
    stage_half(gAb,               A0,        tid);
    stage_half(gAb + 128 * K_DIM, A0 + 8192, tid);
    stage_half(gBb + 128 * K_DIM, B0 + 8192, tid);
    stage_half(gBb + 64,               B1,        tid);
    stage_half(gBb + 64 + 128 * K_DIM, B1 + 8192, tid);
    VMCNT(4);
    BAR();

    for (int i = 0; i < 9; ++i) {
        const f16* gA1 = gAb + (2 * i + 1) * 64;
        const f16* gA2 = gAb + (2 * i + 2) * 64;
        const f16* gB2 = gBb + (2 * i + 2) * 64;
        const f16* gB3 = gBb + (2 * i + 3) * 64;
        iter8<true, 4>(A0, B0, A1, B1, gA1, gA2, gB2, gB3,
                       acc, tid, arow0, brow0, swz);
    }
    // last iteration (tiles 18,19): stage only A19 (F1/F2); publish with vmcnt(0)
    iter8<false, 0>(A0, B0, A1, B1, gAb + 19 * 64, gAb, gBb, gBb,
                    acc, tid, arow0, brow0, swz);

    // ---- epilogue: C = acc + bias.  C/D layout: col=lane&15, row=(lane>>4)*4+j
    int crow0 = mt * 256 + wr * 128;
    int ccol  = nt * 256 + wc * 64 + l15;
    float bz[4];
    #pragma unroll
    for (int fn = 0; fn < 4; ++fn) bz[fn] = bias[ccol + fn * 16];

    #pragma unroll
    for (int fm = 0; fm < 8; ++fm) {
        #pragma unroll
        for (int j = 0; j < 4; ++j) {
            int row = crow0 + fm * 16 + (lane >> 4) * 4 + j;
            if (row < M_ROWS) {
                float* cp = C + (size_t)row * N_COLS + ccol;
                #pragma unroll
                for (int fn = 0; fn < 4; ++fn)
                    cp[fn * 16] = acc[fm][fn][j] + bz[fn];
            }
        }
    }
}

extern "C" void kernel_launch(void* const* d_in, const int* in_sizes, int n_in,
                              void* d_out, int out_size, void* d_ws, size_t ws_size,
                              hipStream_t stream) {
    const float* x      = (const float*)d_in[0];
    const float* weight = (const float*)d_in[1];
    const float* bias   = (const float*)d_in[2];
    float* out     = (float*)d_out;
    float* scale_w = (float*)d_out + (size_t)M_ROWS * N_COLS;

    f16* xq = (f16*)d_ws;
    f16* wq = (f16*)((char*)d_ws + (size_t)M_PAD * K_DIM * sizeof(f16));

    (void)hipFuncSetAttribute((const void*)gemm_kernel,
                              hipFuncAttributeMaxDynamicSharedMemorySize, 131072);

    {
        int wblocks = N_COLS * (K_DIM / 8) / 256;    // 3200
        quant_fused<<<XBLK + wblocks, 256, 0, stream>>>(x, xq, weight, wq, scale_w);
    }
    {
        int grid = (M_PAD / 256) * (N_COLS / 256);   // 47 * 20 = 940
        gemm_kernel<<<grid, 512, 131072, stream>>>(xq, wq, bias, out);
    }
}